// Round 1
// 287.733 us; speedup vs baseline: 1.1782x; 1.1782x over previous
//
#include <hip/hip_runtime.h>
#include <math.h>

#define B_N 16384
#define F_N 128
#define H_N 128
#define E_N 32
#define ROWS (H_N + 1)   // 129 prefix rows per feature
// Interleaved table: tab[f][row][0..31] = A, tab[f][row][32..63] = C  (256 B/row)

typedef float f4v __attribute__((ext_vector_type(4)));

// ---------------------------------------------------------------------------
// Kernel A: per-feature table build. relu(x*w1+b1) is linear in x with one
// breakpoint t = -b1/w1. Sort thresholds; prefix tables over the active set.
// v3: serial 129-step prefix replaced by a group-parallel scan:
//   - 128 threads (32 e-lanes x 4 groups) scan 32 crossings each in place
//   - group offsets added afterwards; all 128 threads write the table rows.
// Serial depth 129 -> 32, writing lanes 32 -> 128.
// ---------------------------------------------------------------------------
__global__ __launch_bounds__(128) void build_tables(
    const float* __restrict__ w1, const float* __restrict__ b1,
    const float* __restrict__ w2, const float* __restrict__ b2,
    float* __restrict__ ts_out, float* __restrict__ tab)
{
    __shared__ float w1s[H_N], b1s[H_N], ts[H_N];
    __shared__ int   hidx[H_N];
    __shared__ float w2s[H_N * E_N];   // 16 KB
    __shared__ float dA[H_N * E_N];    // 16 KB
    __shared__ float dC[H_N * E_N];    // 16 KB
    __shared__ float baseA[4 * E_N], baseC[4 * E_N];
    __shared__ float gtA[4 * E_N], gtC[4 * E_N];

    const int f   = blockIdx.x;
    const int tid = threadIdx.x;

    float w1v = w1[f * H_N + tid];
    float b1v = b1[f * H_N + tid];
    w1s[tid] = w1v;
    b1s[tid] = b1v;
    ts[tid]   = (w1v != 0.0f) ? (-b1v / w1v) : INFINITY;
    hidx[tid] = tid;

    // stage w2[f]: 4096 floats = 1024 float4, 8 per thread, coalesced
    {
        const float4* src = (const float4*)(w2 + (size_t)f * H_N * E_N);
        float4*       dst = (float4*)w2s;
        #pragma unroll
        for (int it = 0; it < 8; ++it) dst[it * 128 + tid] = src[it * 128 + tid];
    }
    __syncthreads();

    // bitonic sort ascending by ts, payload hidx
    for (int k = 2; k <= H_N; k <<= 1) {
        for (int j = k >> 1; j > 0; j >>= 1) {
            int ixj = tid ^ j;
            if (ixj > tid) {
                float a = ts[tid], bv = ts[ixj];
                bool up = ((tid & k) == 0);
                bool sw = up ? (a > bv) : (a < bv);
                if (sw) {
                    int ia = hidx[tid];
                    ts[tid] = bv; ts[ixj] = a;
                    hidx[tid] = hidx[ixj]; hidx[ixj] = ia;
                }
            }
            __syncthreads();
        }
    }

    ts_out[f * H_N + tid] = ts[tid];

    const int e = tid & 31;    // embedding lane
    const int g = tid >> 5;    // 0..3 group

    // crossing deltas, all threads: group g handles sorted positions g*32..+31
    // (each thread only ever re-reads the dA/dC elements it wrote itself, so
    //  no barrier is needed between this and the scan below)
    #pragma unroll 4
    for (int jj = 0; jj < 32; ++jj) {
        int   j   = g * 32 + jj;
        int   p   = hidx[j];
        float w1h = w1s[p], b1h = b1s[p];
        float w2v = w2s[p * E_N + e];
        float s   = (w1h > 0.f) ? 1.f : ((w1h < 0.f) ? -1.f : 0.f);
        dA[j * E_N + e] = s * w1h * w2v;
        dC[j * E_N + e] = s * b1h * w2v;
    }
    // base state at x=-inf: group-partial sums
    {
        float pA = 0.f, pC = 0.f;
        #pragma unroll 4
        for (int hh = 0; hh < 32; ++hh) {
            int   h   = g * 32 + hh;
            float w1h = w1s[h], b1h = b1s[h];
            float w2v = w2s[h * E_N + e];
            if (w1h < 0.f) {
                pA = fmaf(w1h, w2v, pA);
                pC = fmaf(b1h, w2v, pC);
            } else if (w1h == 0.f && b1h > 0.f) {
                pC = fmaf(b1h, w2v, pC);
            }
        }
        baseA[g * E_N + e] = pA;
        baseC[g * E_N + e] = pC;
    }

    // group-local inclusive scan, in place (banks: lanes e 0..31 -> perfect)
    {
        float aA = 0.f, aC = 0.f;
        for (int jj = 0; jj < 32; ++jj) {
            int idx = (g * 32 + jj) * E_N + e;
            aA += dA[idx]; dA[idx] = aA;
            aC += dC[idx]; dC[idx] = aC;
        }
        gtA[g * E_N + e] = aA;
        gtC[g * E_N + e] = aC;
    }
    __syncthreads();

    // offset for group g = full base + totals of groups < g
    float offA = baseA[e] + baseA[E_N + e] + baseA[2 * E_N + e] + baseA[3 * E_N + e];
    float offC = baseC[e] + baseC[E_N + e] + baseC[2 * E_N + e] + baseC[3 * E_N + e]
               + b2[f * E_N + e];
    for (int gg = 0; gg < g; ++gg) {
        offA += gtA[gg * E_N + e];
        offC += gtC[gg * E_N + e];
    }

    const size_t base = (size_t)f * ROWS * 64;
    if (g == 0) {                       // row 0 = base state
        tab[base + e]      = offA;
        tab[base + 32 + e] = offC;
    }
    // rows g*32+1 .. g*32+32, written by all 128 threads
    #pragma unroll 4
    for (int jj = 0; jj < 32; ++jj) {
        int j = g * 32 + jj;
        tab[base + (size_t)(j + 1) * 64 + e]      = offA + dA[j * E_N + e];
        tab[base + (size_t)(j + 1) * 64 + 32 + e] = offC + dC[j * E_N + e];
    }
}

// ---------------------------------------------------------------------------
// Kernel B: out[b,f,e] = x*A[f,r,e] + C[f,r,e], r = lower_bound(ts_f, x).
// v3: (1) search-dedup: each (row,feature) searched ONCE (was 8x redundant,
//     one per e-quad), results parked in LDS;
//     (2) NON-TEMPORAL output stores: the 268 MB write stream no longer
//     evicts the 2.1 MB table from L2 -> gathers stay L2-hits;
//     (3) XCD-contiguous block remap: each XCD's L2 only needs one feature
//     group's 1 MB table slice (was all 4.2 MB vs 4 MiB L2 capacity).
// ---------------------------------------------------------------------------
#define FH 32   // features per block
#define NB 64   // batch rows per block

__global__ __launch_bounds__(256, 4) void apply_tables(
    const float* __restrict__ x, const float* __restrict__ ts,
    const float* __restrict__ tab, float* __restrict__ out)
{
    __shared__ float lds_t[FH * ROWS];   // 16.5 KB
    __shared__ float xs[NB * FH];        // 8 KB
    __shared__ int   los[NB * FH];       // 8 KB   (32.5 KB total -> 4 blk/CU)

    const int tid = threadIdx.x;

    // XCD-contiguous remap: blockIdx round-robins over the 8 XCDs, so give
    // XCD k the contiguous work ids [128k, 128k+128) -> one feature group
    // (by = k/2) per XCD, table slice stays L2-resident.
    const unsigned bid  = blockIdx.x;                  // 1024 linear blocks
    const unsigned work = (bid & 7u) * 128u + (bid >> 3);
    const int b0 = (int)(work & 255u) * NB;            // batch tile
    const int f0 = (int)(work >> 8)  * FH;             // feature group

    // stage sorted thresholds: FH*128 = 4096 floats = 1024 float4
    {
        const float4* src = (const float4*)(ts + (size_t)f0 * H_N);
        #pragma unroll
        for (int it = 0; it < 4; ++it) {
            int    vi  = it * 256 + tid;
            float4 v   = src[vi];
            int    idx = vi * 4;
            int    fl  = idx >> 7;       // /128
            int    j   = idx & 127;
            float* dst = &lds_t[fl * ROWS + j];
            dst[0] = v.x; dst[1] = v.y; dst[2] = v.z; dst[3] = v.w;
        }
    }
    // stage x tile: NB x FH = 2048 floats = 512 float4
    {
        #pragma unroll
        for (int it = 0; it < 2; ++it) {
            int vi = it * 256 + tid;
            int bl = vi >> 3;            // 8 float4 per row of 32
            int fq = (vi & 7) * 4;
            float4 v = *(const float4*)(x + (size_t)(b0 + bl) * F_N + f0 + fq);
            *(float4*)(&xs[bl * FH + fq]) = v;
        }
    }
    __syncthreads();

    // Phase A: binary search once per (row, feature): 2048 searches/block,
    // 8 per thread, step-major for 8-wide LDS ILP.
    {
        const int fa = tid & 31;         // feature lane
        const int rg = tid >> 5;         // 0..7, rows rg*8..rg*8+7
        const float* tloc = &lds_t[fa * ROWS];
        float xv[8];
        int   lo[8], hi[8];
        #pragma unroll
        for (int j = 0; j < 8; ++j) {
            xv[j] = xs[(rg * 8 + j) * FH + fa];
            lo[j] = 0; hi[j] = H_N;
        }
        #pragma unroll
        for (int s = 0; s < 7; ++s) {
            #pragma unroll
            for (int j = 0; j < 8; ++j) {
                int  mid = (lo[j] + hi[j]) >> 1;
                bool lt  = tloc[mid] < xv[j];
                lo[j] = lt ? mid + 1 : lo[j];
                hi[j] = lt ? hi[j] : mid;
            }
        }
        #pragma unroll
        for (int j = 0; j < 8; ++j) los[(rg * 8 + j) * FH + fa] = lo[j];
    }
    __syncthreads();

    // Phase B: gather + FMA + non-temporal coalesced stores.
    const int fl = tid >> 3;             // 0..31 feature lane
    const int eq = tid & 7;              // 0..7 e-quad
    const int fg = f0 + fl;
    const float* tb = tab + (size_t)fg * ROWS * 64 + eq * 4;
    float*       op = out + (size_t)b0 * (F_N * E_N) + (size_t)fg * E_N + eq * 4;

    #pragma unroll 4
    for (int r = 0; r < NB; ++r) {
        int   lo = los[r * FH + fl];     // broadcast within e-quad group
        float xv = xs[r * FH + fl];
        const float* row = tb + (size_t)lo * 64;
        f4v a4 = *(const f4v*)(row);
        f4v c4 = *(const f4v*)(row + 32);
        f4v o;
        o.x = fmaf(xv, a4.x, c4.x);
        o.y = fmaf(xv, a4.y, c4.y);
        o.z = fmaf(xv, a4.z, c4.z);
        o.w = fmaf(xv, a4.w, c4.w);
        __builtin_nontemporal_store(o, (f4v*)(op + (size_t)r * (F_N * E_N)));
    }
}

// ---------------------------------------------------------------------------
// Fallback (only if d_ws is too small): direct fp32 compute.
// ---------------------------------------------------------------------------
__global__ __launch_bounds__(256) void direct_kernel(
    const float* __restrict__ x, const float* __restrict__ w1,
    const float* __restrict__ b1, const float* __restrict__ w2,
    const float* __restrict__ b2, float* __restrict__ out)
{
    __shared__ float w1s[H_N], b1s[H_N], b2s[E_N];
    __shared__ float w2s[H_N * E_N];
    const int f   = blockIdx.y;
    const int tid = threadIdx.x;
    if (tid < H_N) { w1s[tid] = w1[f * H_N + tid]; b1s[tid] = b1[f * H_N + tid]; }
    for (int i = tid; i < H_N * E_N; i += 256) w2s[i] = w2[(size_t)f * H_N * E_N + i];
    if (tid < E_N) b2s[tid] = b2[f * E_N + tid];
    __syncthreads();

    const int b  = blockIdx.x * 256 + tid;
    float xv = x[(size_t)b * F_N + f];
    float acc[E_N];
    #pragma unroll
    for (int e = 0; e < E_N; ++e) acc[e] = b2s[e];
    for (int h = 0; h < H_N; ++h) {
        float hv = fmaxf(fmaf(xv, w1s[h], b1s[h]), 0.f);
        #pragma unroll
        for (int e = 0; e < E_N; ++e) acc[e] = fmaf(hv, w2s[h * E_N + e], acc[e]);
    }
    float* op = out + (size_t)b * (F_N * E_N) + (size_t)f * E_N;
    #pragma unroll
    for (int e = 0; e < E_N; e += 4)
        *(float4*)(op + e) = make_float4(acc[e], acc[e + 1], acc[e + 2], acc[e + 3]);
}

extern "C" void kernel_launch(void* const* d_in, const int* in_sizes, int n_in,
                              void* d_out, int out_size, void* d_ws, size_t ws_size,
                              hipStream_t stream) {
    const float* x  = (const float*)d_in[0];
    const float* w1 = (const float*)d_in[1];
    const float* b1 = (const float*)d_in[2];
    const float* w2 = (const float*)d_in[3];
    const float* b2 = (const float*)d_in[4];
    float* out = (float*)d_out;

    const size_t n_ts  = (size_t)F_N * H_N;
    const size_t n_tab = (size_t)F_N * ROWS * 64;
    const size_t need  = (n_ts + n_tab) * sizeof(float);

    if (ws_size >= need) {
        float* ts  = (float*)d_ws;
        float* tab = ts + n_ts;
        build_tables<<<dim3(F_N), dim3(128), 0, stream>>>(w1, b1, w2, b2, ts, tab);
        apply_tables<<<dim3((B_N / NB) * (F_N / FH)), dim3(256), 0, stream>>>(x, ts, tab, out);
    } else {
        direct_kernel<<<dim3(B_N / 256, F_N), dim3(256), 0, stream>>>(x, w1, b1, w2, b2, out);
    }
}